// Round 4
// baseline (41.040 us; speedup 1.0000x reference)
//
#include <hip/hip_runtime.h>
#include <cmath>

#define NCLS 6
#define GRP 256
#define DIM 256

// ---------------- K0: per-class feature transpose ----------------
// ft[(c*256 + d)*256 + k] = feat[(c*256 + k)*256 + d]
__global__ __launch_bounds__(256) void transpose_kernel(
    const float* __restrict__ feat, float* __restrict__ ft)
{
    __shared__ float tile[64][65];
    const int b  = blockIdx.x;
    const int c  = b >> 4;
    const int tt = b & 15;
    const int r0 = (tt >> 2) << 6;   // k tile origin
    const int c0 = (tt & 3) << 6;    // d tile origin
    const int t  = threadIdx.x;

    #pragma unroll
    for (int q = 0; q < 4; ++q) {
        int idx  = q * 256 + t;
        int row  = idx >> 4;
        int col4 = (idx & 15) << 2;
        float4 v = *reinterpret_cast<const float4*>(
            feat + (size_t)(c * 256 + r0 + row) * DIM + c0 + col4);
        tile[row][col4 + 0] = v.x; tile[row][col4 + 1] = v.y;
        tile[row][col4 + 2] = v.z; tile[row][col4 + 3] = v.w;
    }
    __syncthreads();
    #pragma unroll
    for (int q = 0; q < 4; ++q) {
        int idx = q * 256 + t;
        int dd  = idx >> 4;
        int r4  = (idx & 15) << 2;
        float4 o = make_float4(tile[r4][dd], tile[r4 + 1][dd],
                               tile[r4 + 2][dd], tile[r4 + 3][dd]);
        *reinterpret_cast<float4*>(
            ft + (size_t)(c * 256 + c0 + dd) * GRP + r0 + r4) = o;
    }
}

// ---------------- K1: dist + labels -> LE[a][k] = (L, lg = -dist/2) ----------------
// 768 blocks: class c (128 blocks each): anchor-quad q = (b&127)>>1, k-half h = b&1.
// Thread: col = t&127 (k = h*128+col), d-half dh = t>>7. Anchor values are
// wave-uniform -> scalar loads; column loads coalesced from transposed ft.
__global__ __launch_bounds__(256) void dist_label_kernel(
    const float* __restrict__ feat,
    const float* __restrict__ ft,
    const float* __restrict__ green,
    const float* __restrict__ red,
    const float* __restrict__ trans,
    const int*   __restrict__ sym,
    float2* __restrict__ LE)           // [1536*256] (L, lg)
{
    __shared__ float part[2][4][128];

    const int b   = blockIdx.x;
    const int c   = b >> 7;
    const int r   = b & 127;
    const int q   = r >> 1;
    const int h   = r & 1;
    const int t   = threadIdx.x;
    const int col = t & 127;
    const int dh  = t >> 7;            // wave-uniform
    const int a0g = (c << 8) + (q << 2);
    const int k   = (h << 7) + col;
    const int kg  = (c << 8) + k;

    const float* f0 = feat + (size_t)a0g * DIM + (dh << 7);  // uniform per wave
    const float* cp = ft + ((size_t)((c << 8) + (dh << 7))) * GRP + k;

    float ac0 = 0.f, ac1 = 0.f, ac2 = 0.f, ac3 = 0.f;
    #pragma unroll 8
    for (int d = 0; d < 128; ++d) {
        float v = cp[(size_t)d * GRP];   // coalesced 256B/wave
        float x;
        x = f0[d]       - v; ac0 = fmaf(x, x, ac0);   // f0[*] wave-uniform -> s_load
        x = f0[256 + d] - v; ac1 = fmaf(x, x, ac1);
        x = f0[512 + d] - v; ac2 = fmaf(x, x, ac2);
        x = f0[768 + d] - v; ac3 = fmaf(x, x, ac3);
    }
    part[dh][0][col] = ac0; part[dh][1][col] = ac1;
    part[dh][2][col] = ac2; part[dh][3][col] = ac3;
    __syncthreads();

    // thread now owns anchors {p, p+2} for its col
    const int p = dh;
    float s0 = part[0][p][col]     + part[1][p][col];
    float s1 = part[0][p + 2][col] + part[1][p + 2][col];
    float lg0 = -0.5f * sqrtf(s0 + 1e-12f);
    float lg1 = -0.5f * sqrtf(s1 + 1e-12f);

    // k-side labels (shared by both anchors)
    float kgx = green[3 * kg], kgy = green[3 * kg + 1], kgz = green[3 * kg + 2];
    float ktx = trans[3 * kg], kty = trans[3 * kg + 1], ktz = trans[3 * kg + 2];
    float krx = 0.f, kry = 0.f, krz = 0.f;
    int ksym = 0;
    if (c >= 2) { krx = red[3 * kg]; kry = red[3 * kg + 1]; krz = red[3 * kg + 2]; }
    if (c == 5) { ksym = sym[4 * kg]; }

    #pragma unroll
    for (int e = 0; e < 2; ++e) {
        const int ag = a0g + p + 2 * e;          // wave-uniform anchor row
        float l1g = fabsf(green[3*ag] - kgx) + fabsf(green[3*ag+1] - kgy)
                  + fabsf(green[3*ag+2] - kgz);
        float l1t = fabsf(trans[3*ag] - ktx) + fabsf(trans[3*ag+1] - kty)
                  + fabsf(trans[3*ag+2] - ktz);
        float L;
        if (c < 2) {
            L = 0.8f * l1g + 0.2f * l1t;
        } else {
            float l1r = fabsf(red[3*ag] - krx) + fabsf(red[3*ag+1] - kry)
                      + fabsf(red[3*ag+2] - krz);
            float rot;
            if (c < 5) {
                rot = 0.5f * (l1g + l1r);
            } else {
                float both = ((sym[4*ag] == 0) && (ksym == 0)) ? 1.f : 0.f;
                rot = (l1g + both * l1r) / (1.f + both);
            }
            L = 0.8f * rot + 0.2f * l1t;
        }
        LE[(size_t)ag * GRP + k] = make_float2(L, e == 0 ? lg0 : lg1);
    }
}

// ---------------- K2: denom + log-prob sum, 1 anchor/block ----------------
// 1536 blocks x 256 thr. Wave w scans k in [64w,64w+64) (J=4 j's per lane),
// partial denominators combined across waves in LDS.
__global__ __launch_bounds__(256) void denom_kernel(
    const float2* __restrict__ LE,
    float* __restrict__ partial)
{
    __shared__ __align__(16) float2 LEs[GRP];    // (L, ev)
    __shared__ __align__(16) float pd[GRP][4];   // per-wave partial denoms
    __shared__ float rbuf[4];

    const int a = blockIdx.x;
    const int i = a & 255;
    const int t = threadIdx.x;
    const int w = t >> 6;
    const int l = t & 63;

    float2 g = LE[(size_t)a * GRP + t];          // coalesced 8B/lane
    const float lgt = g.y;                        // own numerator logit (j = t)
    LEs[t] = make_float2(g.x, __expf(g.y));
    __syncthreads();

    // owned j's across the full k-range: j = l + 64*jj
    float L0 = LEs[l].x;
    float L1 = LEs[l + 64].x;
    float L2 = LEs[l + 128].x;
    float L3 = LEs[l + 192].x;

    const float4* p4 = reinterpret_cast<const float4*>(LEs);
    float dn0 = 0.f, dn1 = 0.f, dn2 = 0.f, dn3 = 0.f;
    const int q0 = w << 5;
    #pragma unroll 8
    for (int q = q0; q < q0 + 32; ++q) {
        float4 u = p4[q];                         // uniform broadcast: (L,ev)x2
        dn0 += (u.x >= L0) ? u.y : 0.f;  dn0 += (u.z >= L0) ? u.w : 0.f;
        dn1 += (u.x >= L1) ? u.y : 0.f;  dn1 += (u.z >= L1) ? u.w : 0.f;
        dn2 += (u.x >= L2) ? u.y : 0.f;  dn2 += (u.z >= L2) ? u.w : 0.f;
        dn3 += (u.x >= L3) ? u.y : 0.f;  dn3 += (u.z >= L3) ? u.w : 0.f;
    }
    pd[l][w]       = dn0;
    pd[l + 64][w]  = dn1;
    pd[l + 128][w] = dn2;
    pd[l + 192][w] = dn3;
    __syncthreads();

    float4 dns = *reinterpret_cast<const float4*>(pd[t]);
    float dn = (dns.x + dns.y) + (dns.z + dns.w);
    float part = (t != i) ? (lgt - __logf(dn)) : 0.f;

    #pragma unroll
    for (int off = 32; off > 0; off >>= 1)
        part += __shfl_xor(part, off);
    if (l == 0) rbuf[w] = part;
    __syncthreads();
    if (t == 0) partial[a] = (rbuf[0] + rbuf[1]) + (rbuf[2] + rbuf[3]);
}

// ---------------- K3: finalize ----------------
__global__ __launch_bounds__(256) void rnc_finalize_kernel(
    const float* __restrict__ partial, float* __restrict__ out)
{
    __shared__ float rbuf[4];
    int t = threadIdx.x;
    float acc = 0.f;
    for (int k = t; k < NCLS * GRP; k += 256) acc += partial[k];
    #pragma unroll
    for (int off = 32; off > 0; off >>= 1)
        acc += __shfl_down(acc, off);
    if ((t & 63) == 0) rbuf[t >> 6] = acc;
    __syncthreads();
    if (t == 0)
        out[0] = -(rbuf[0] + rbuf[1] + rbuf[2] + rbuf[3]) / (256.f * 255.f * 6.f);
}

extern "C" void kernel_launch(void* const* d_in, const int* in_sizes, int n_in,
                              void* d_out, int out_size, void* d_ws, size_t ws_size,
                              hipStream_t stream)
{
    const float* feat  = (const float*)d_in[0];
    // d_in[1] = labels: unused (classes are contiguous GROUP-sized slices)
    const float* green = (const float*)d_in[2];
    const float* red   = (const float*)d_in[3];
    const float* trans = (const float*)d_in[4];
    const int*   sym   = (const int*)d_in[5];

    float*  wsf     = (float*)d_ws;
    float*  partial = wsf;                           // 1536 floats
    float*  ft      = wsf + 2048;                    // 393216 floats
    float2* LE      = (float2*)(wsf + 2048 + NCLS * GRP * DIM);  // 1536*256 float2
    float*  out     = (float*)d_out;

    transpose_kernel<<<NCLS * 16, 256, 0, stream>>>(feat, ft);
    dist_label_kernel<<<NCLS * 128, 256, 0, stream>>>(feat, ft, green, red, trans, sym, LE);
    denom_kernel<<<NCLS * GRP, 256, 0, stream>>>(LE, partial);
    rnc_finalize_kernel<<<1, 256, 0, stream>>>(partial, out);
}

// Round 5
// 31.213 us; speedup vs baseline: 1.3149x; 1.3149x over previous
//
#include <hip/hip_runtime.h>
#include <cmath>

#define NCLS 6
#define GRP 256
#define DIM 256
#define NBLK (NCLS * 64)   // 384 main blocks

// ws layout (floats): [0..384) partial, [512] counter (uint), [2048..) ft

// ---------------- K0: per-class feature transpose (+ counter zero) ----------------
// ft[(c*256 + d)*256 + k] = feat[(c*256 + k)*256 + d]
__global__ __launch_bounds__(256) void transpose_kernel(
    const float* __restrict__ feat, float* __restrict__ ft,
    unsigned int* __restrict__ counter)
{
    __shared__ float tile[64][65];
    const int b  = blockIdx.x;
    const int c  = b >> 4;
    const int tt = b & 15;
    const int r0 = (tt >> 2) << 6;   // k tile origin
    const int c0 = (tt & 3) << 6;    // d tile origin
    const int t  = threadIdx.x;

    if (b == 0 && t == 0)
        __hip_atomic_store(counter, 0u, __ATOMIC_RELAXED, __HIP_MEMORY_SCOPE_AGENT);

    #pragma unroll
    for (int q = 0; q < 4; ++q) {
        int idx  = q * 256 + t;
        int row  = idx >> 4;
        int col4 = (idx & 15) << 2;
        float4 v = *reinterpret_cast<const float4*>(
            feat + (size_t)(c * 256 + r0 + row) * DIM + c0 + col4);
        tile[row][col4 + 0] = v.x; tile[row][col4 + 1] = v.y;
        tile[row][col4 + 2] = v.z; tile[row][col4 + 3] = v.w;
    }
    __syncthreads();
    #pragma unroll
    for (int q = 0; q < 4; ++q) {
        int idx = q * 256 + t;
        int dd  = idx >> 4;
        int r4  = (idx & 15) << 2;
        float4 o = make_float4(tile[r4][dd], tile[r4 + 1][dd],
                               tile[r4 + 2][dd], tile[r4 + 3][dd]);
        *reinterpret_cast<float4*>(
            ft + (size_t)(c * 256 + c0 + dd) * GRP + r0 + r4) = o;
    }
}

// ---------------- K1: fused dist + labels + denom + full reduction ----------------
// 384 blocks x 512 threads (8 waves). 4 anchors per block.
// Phase 1: thread (col=t&255, dh=t>>8) accumulates dist^2 of 4 anchors vs
//          column col over d-half dh (coalesced ft loads, uniform LDS broadcast).
// Phase 2: labels+ev per (anchor, col). Phase 3: wave (p=w&3, hh=w>>2) scans
//          k-half hh for anchor p, 4 j's per lane. Last block reduces partial[].
__global__ __launch_bounds__(512) void rnc_main_kernel(
    const float* __restrict__ ft,      // transposed features
    const float* __restrict__ feat,
    const float* __restrict__ green,
    const float* __restrict__ red,
    const float* __restrict__ trans,
    const int*   __restrict__ sym,
    float* __restrict__ partial,       // [384]
    unsigned int* __restrict__ counter,
    float* __restrict__ out)
{
    __shared__ __align__(16) float4 fi4[2][128];     // [dh][d'] anchor quad packed
    __shared__ float part[2][4][GRP];                // [dh][p][col] dist^2 partials
    __shared__ __align__(16) float2 LEs[4][GRP];     // (L, ev)
    __shared__ float lgs[4][GRP];                    // lg = -dist/2
    __shared__ __align__(16) float pdn[4][GRP][2];   // per-k-half denom partials
    __shared__ float rbuf[8];
    __shared__ int iswin;

    const int b    = blockIdx.x;
    const int c    = b >> 6;           // class
    const int a0   = (b & 63) << 2;    // first in-class anchor
    const int base = c << 8;
    const int a0g  = base + a0;
    const int t    = threadIdx.x;

    // stage anchor quad: fi4[dh][d'] = F[a0g..a0g+3][dh*128+d']
    if (t < 256) {
        float x0 = feat[(size_t)(a0g + 0) * DIM + t];
        float x1 = feat[(size_t)(a0g + 1) * DIM + t];
        float x2 = feat[(size_t)(a0g + 2) * DIM + t];
        float x3 = feat[(size_t)(a0g + 3) * DIM + t];
        fi4[t >> 7][t & 127] = make_float4(x0, x1, x2, x3);
    }
    __syncthreads();

    const int col = t & 255;
    const int dh  = t >> 8;            // wave-uniform (waves 0-3: 0, waves 4-7: 1)

    // ---- phase 1: dist^2 partials ----
    {
        const float*  cp = ft + (size_t)((c << 8) + (dh << 7)) * GRP + col;
        const float4* fb = fi4[dh];
        float ac0 = 0.f, ac1 = 0.f, ac2 = 0.f, ac3 = 0.f;
        #pragma unroll 8
        for (int d = 0; d < 128; ++d) {
            float v  = cp[(size_t)d * GRP];   // coalesced 256B/wave from L2
            float4 f = fb[d];                 // uniform LDS broadcast
            float x;
            x = f.x - v; ac0 = fmaf(x, x, ac0);
            x = f.y - v; ac1 = fmaf(x, x, ac1);
            x = f.z - v; ac2 = fmaf(x, x, ac2);
            x = f.w - v; ac3 = fmaf(x, x, ac3);
        }
        part[dh][0][col] = ac0;
        part[dh][1][col] = ac1;
        part[dh][2][col] = ac2;
        part[dh][3][col] = ac3;
    }
    __syncthreads();

    // ---- phase 2: combine halves, labels, ev; thread handles anchors {dh, dh+2} ----
    {
        const int kg = base + col;
        float kgx = green[3*kg], kgy = green[3*kg+1], kgz = green[3*kg+2];
        float ktx = trans[3*kg], kty = trans[3*kg+1], ktz = trans[3*kg+2];
        float krx = 0.f, kry = 0.f, krz = 0.f;
        int ksym = 0;
        if (c >= 2) { krx = red[3*kg]; kry = red[3*kg+1]; krz = red[3*kg+2]; }
        if (c == 5) ksym = sym[4*kg];

        #pragma unroll
        for (int e = 0; e < 2; ++e) {
            const int p  = dh + 2 * e;     // wave-uniform
            const int ag = a0g + p;
            float s  = part[0][p][col] + part[1][p][col];
            float lg = -0.5f * sqrtf(s + 1e-12f);

            float l1g = fabsf(green[3*ag] - kgx) + fabsf(green[3*ag+1] - kgy)
                      + fabsf(green[3*ag+2] - kgz);
            float l1t = fabsf(trans[3*ag] - ktx) + fabsf(trans[3*ag+1] - kty)
                      + fabsf(trans[3*ag+2] - ktz);
            float L;
            if (c < 2) {
                L = 0.8f * l1g + 0.2f * l1t;
            } else {
                float l1r = fabsf(red[3*ag] - krx) + fabsf(red[3*ag+1] - kry)
                          + fabsf(red[3*ag+2] - krz);
                float rot;
                if (c < 5) {
                    rot = 0.5f * (l1g + l1r);
                } else {
                    float both = ((sym[4*ag] == 0) && (ksym == 0)) ? 1.f : 0.f;
                    rot = (l1g + both * l1r) / (1.f + both);
                }
                L = 0.8f * rot + 0.2f * l1t;
            }
            LEs[p][col] = make_float2(L, __expf(lg));
            lgs[p][col] = lg;
        }
    }
    __syncthreads();

    // ---- phase 3: denom scan. wave w: anchor p = w&3, k-half hh = w>>2 ----
    const int w  = t >> 6;
    const int l  = t & 63;
    const int p  = w & 3;
    const int hh = w >> 2;

    float L0 = LEs[p][l].x;
    float L1 = LEs[p][l + 64].x;
    float L2 = LEs[p][l + 128].x;
    float L3 = LEs[p][l + 192].x;

    const float4* q4 = reinterpret_cast<const float4*>(LEs[p]);
    float dn0 = 0.f, dn1 = 0.f, dn2 = 0.f, dn3 = 0.f;
    #pragma unroll 8
    for (int q = hh * 64; q < hh * 64 + 64; ++q) {
        float4 u = q4[q];                 // uniform broadcast: (L,ev) x2
        dn0 += (u.x >= L0) ? u.y : 0.f;  dn0 += (u.z >= L0) ? u.w : 0.f;
        dn1 += (u.x >= L1) ? u.y : 0.f;  dn1 += (u.z >= L1) ? u.w : 0.f;
        dn2 += (u.x >= L2) ? u.y : 0.f;  dn2 += (u.z >= L2) ? u.w : 0.f;
        dn3 += (u.x >= L3) ? u.y : 0.f;  dn3 += (u.z >= L3) ? u.w : 0.f;
    }
    pdn[p][l][hh]       = dn0;
    pdn[p][l + 64][hh]  = dn1;
    pdn[p][l + 128][hh] = dn2;
    pdn[p][l + 192][hh] = dn3;
    __syncthreads();

    // ---- combine + log-prob sum over the block's 4 anchors ----
    float acc = 0.f;
    #pragma unroll
    for (int e = 0; e < 2; ++e) {
        int idx = t + e * 512;            // 1024 (p,j) pairs over 512 threads
        int pp  = idx >> 8;
        int j   = idx & 255;
        float dn = pdn[pp][j][0] + pdn[pp][j][1];
        float v  = lgs[pp][j] - __logf(dn);
        acc += (j != a0 + pp) ? v : 0.f;
    }
    #pragma unroll
    for (int off = 32; off > 0; off >>= 1)
        acc += __shfl_xor(acc, off);
    if (l == 0) rbuf[w] = acc;
    __syncthreads();
    if (t == 0) {
        float s = 0.f;
        #pragma unroll
        for (int k = 0; k < 8; ++k) s += rbuf[k];
        __hip_atomic_store(&partial[b], s, __ATOMIC_RELAXED, __HIP_MEMORY_SCOPE_AGENT);
        unsigned int old = __hip_atomic_fetch_add(counter, 1u, __ATOMIC_ACQ_REL,
                                                  __HIP_MEMORY_SCOPE_AGENT);
        iswin = (old == NBLK - 1) ? 1 : 0;
    }
    __syncthreads();

    // ---- last block: final deterministic reduction ----
    if (iswin) {
        float a2 = 0.f;
        if (t < NBLK)
            a2 = __hip_atomic_load(&partial[t], __ATOMIC_RELAXED, __HIP_MEMORY_SCOPE_AGENT);
        #pragma unroll
        for (int off = 32; off > 0; off >>= 1)
            a2 += __shfl_xor(a2, off);
        if (l == 0) rbuf[w] = a2;
        __syncthreads();
        if (t == 0) {
            float s = 0.f;
            #pragma unroll
            for (int k = 0; k < 8; ++k) s += rbuf[k];
            out[0] = -s / (256.f * 255.f * 6.f);
        }
    }
}

extern "C" void kernel_launch(void* const* d_in, const int* in_sizes, int n_in,
                              void* d_out, int out_size, void* d_ws, size_t ws_size,
                              hipStream_t stream)
{
    const float* feat  = (const float*)d_in[0];
    // d_in[1] = labels: unused (classes are contiguous GROUP-sized slices)
    const float* green = (const float*)d_in[2];
    const float* red   = (const float*)d_in[3];
    const float* trans = (const float*)d_in[4];
    const int*   sym   = (const int*)d_in[5];

    float*        wsf     = (float*)d_ws;
    float*        partial = wsf;                         // 384 floats
    unsigned int* counter = (unsigned int*)(wsf + 512);  // 1 uint
    float*        ft      = wsf + 2048;                  // 6*256*256 floats
    float*        out     = (float*)d_out;

    transpose_kernel<<<NCLS * 16, 256, 0, stream>>>(feat, ft, counter);
    rnc_main_kernel<<<NBLK, 512, 0, stream>>>(ft, feat, green, red, trans, sym,
                                              partial, counter, out);
}